// Round 10
// baseline (39741.522 us; speedup 1.0000x reference)
//
#include <hip/hip_runtime.h>
#include <hip/hip_bf16.h>

#define B_   256
#define T_   64
#define OBS_ 1024
#define ACT_ 6
#define STO_ 32
#define HID_ 1024

using bf16 = __bf16;
typedef __attribute__((ext_vector_type(8))) __bf16 bf16x8;
typedef __attribute__((ext_vector_type(4))) float f32x4;
typedef unsigned long long u64;

__device__ __forceinline__ f32x4 MF(bf16x8 a, bf16x8 b, f32x4 c) {
  return __builtin_amdgcn_mfma_f32_16x16x32_bf16(a, b, c, 0, 0, 0);
}

// ---- per-access coherent (sc0/sc1) data movement: NO cache-wide fences ----
__device__ __forceinline__ float ldf(const float* p) {
  return __hip_atomic_load(p, __ATOMIC_RELAXED, __HIP_MEMORY_SCOPE_AGENT);
}
__device__ __forceinline__ void stf(float* p, float v) {
  __hip_atomic_store(p, v, __ATOMIC_RELAXED, __HIP_MEMORY_SCOPE_AGENT);
}
__device__ __forceinline__ bf16x8 ld8bf(const float* p) {  // 8 f32 (32B) -> bf16x8
  const u64* q = (const u64*)p;
  u64 a0 = __hip_atomic_load(q + 0, __ATOMIC_RELAXED, __HIP_MEMORY_SCOPE_AGENT);
  u64 a1 = __hip_atomic_load(q + 1, __ATOMIC_RELAXED, __HIP_MEMORY_SCOPE_AGENT);
  u64 a2 = __hip_atomic_load(q + 2, __ATOMIC_RELAXED, __HIP_MEMORY_SCOPE_AGENT);
  u64 a3 = __hip_atomic_load(q + 3, __ATOMIC_RELAXED, __HIP_MEMORY_SCOPE_AGENT);
  bf16x8 r;
  r[0] = (bf16)__uint_as_float((unsigned)a0); r[1] = (bf16)__uint_as_float((unsigned)(a0 >> 32));
  r[2] = (bf16)__uint_as_float((unsigned)a1); r[3] = (bf16)__uint_as_float((unsigned)(a1 >> 32));
  r[4] = (bf16)__uint_as_float((unsigned)a2); r[5] = (bf16)__uint_as_float((unsigned)(a2 >> 32));
  r[6] = (bf16)__uint_as_float((unsigned)a3); r[7] = (bf16)__uint_as_float((unsigned)(a3 >> 32));
  return r;
}

// relaxed poll (no acquire -> no L2 invalidate); data loads are sc1 so always fresh
__device__ __forceinline__ void waitctr(unsigned* c, unsigned tgt) {
  if (threadIdx.x == 0) {
    while (__hip_atomic_load(c, __ATOMIC_RELAXED, __HIP_MEMORY_SCOPE_AGENT) < tgt)
      __builtin_amdgcn_s_sleep(1);
  }
  __syncthreads();
  asm volatile("" ::: "memory");
}
// release-add: waves drain stores at __syncthreads, then publish
__device__ __forceinline__ void signalctr(unsigned* c) {
  __syncthreads();
  if (threadIdx.x == 0)
    __hip_atomic_fetch_add(c, 1u, __ATOMIC_RELEASE, __HIP_MEMORY_SCOPE_AGENT);
}

struct PP {
  const bf16 *w_in2, *w_wih, *w_whh, *w_pr1, *w_pr2, *w_po1h, *w_po1o, *w_po2, *w_head;
  const bf16 *obsb;
  const float *b_in2, *b_ih, *b_hh, *b_pr1, *b_pr2, *b_po1, *b_po2;
  const float *pr_mb, *pr_sb, *po_mb, *po_sb;
  const float *eps, *act, *in_w1, *in_b1;
  float *x1f, *x2f, *q1f, *p1f, *q2f, *p2f, *hfA, *hfB;
  float *feat, *pm, *ps, *qm, *qs;
  unsigned *ctr;
};
// counters: ctr[t*32 + kind*4 + mt]; kinds: 0 x2(tgt4) 1 h(8) 2 q1(4) 3 p1(4) 4 q2(4) 5 p2(4) 6 x1(4)

// 64m x 256n GEMM, 8 waves, A fp32-coherent, optional bf16 second K-segment; relu; stf out
template<int SEG2>
__device__ __forceinline__ void gemmS(
    const float* __restrict__ A1, const bf16* __restrict__ A2, size_t lda2,
    const bf16* __restrict__ W1, const bf16* __restrict__ W2,
    int m0, int ncol0, const float* __restrict__ bias, float* __restrict__ outf) {
  const int tid = threadIdx.x, lane = tid & 63, wv = tid >> 6;
  const int l15 = lane & 15, kg = lane >> 4, kq = kg << 3, rq = kg << 2;
  const int mrow = m0 + (wv & 3) * 16;
  const int nb = ncol0 + (wv >> 2) * 128;
  f32x4 acc[8];
  #pragma unroll
  for (int nf = 0; nf < 8; ++nf) acc[nf] = f32x4{0.f, 0.f, 0.f, 0.f};
  {
    const float* __restrict__ ap = A1 + (size_t)(mrow + l15) * 1024 + kq;
    const bf16* __restrict__ wp = W1 + (size_t)(nb + l15) * 1024 + kq;
    #pragma unroll 2
    for (int k = 0; k < 1024; k += 32) {
      bf16x8 af = ld8bf(ap + k);
      #pragma unroll
      for (int nf = 0; nf < 8; ++nf)
        acc[nf] = MF(af, *(const bf16x8*)(wp + k + (size_t)nf * 16384), acc[nf]);
    }
  }
  if (SEG2) {
    const bf16* __restrict__ ap2 = A2 + (size_t)(mrow + l15) * lda2 + kq;
    const bf16* __restrict__ wp2 = W2 + (size_t)(nb + l15) * 1024 + kq;
    #pragma unroll 2
    for (int k = 0; k < 1024; k += 32) {
      bf16x8 af = *(const bf16x8*)(ap2 + k);
      #pragma unroll
      for (int nf = 0; nf < 8; ++nf)
        acc[nf] = MF(af, *(const bf16x8*)(wp2 + k + (size_t)nf * 16384), acc[nf]);
    }
  }
  #pragma unroll
  for (int nf = 0; nf < 8; ++nf) {
    const int col = nb + nf * 16 + l15;
    const float bv = bias[col];
    #pragma unroll
    for (int r = 0; r < 4; ++r) {
      const int row = mrow + rq + r;
      stf(outf + (size_t)row * 1024 + col, fmaxf(acc[nf][r] + bv, 0.f));
    }
  }
}

__global__ __launch_bounds__(512, 1) void k_rssm(PP P) {
  __shared__ float sh[10048 + 1664];   // S5 scratch
  const int bid = blockIdx.x, tid = threadIdx.x;
  const int lane = tid & 63, wv = tid >> 6;
  const int l15 = lane & 15, kg = lane >> 4, kq = kg << 3, rq = kg << 2;

  for (int t = 0; t < T_; ++t) {
    float* hfCur = (t & 1) ? P.hfB : P.hfA;
    const float* hfPrev = (t & 1) ? P.hfA : P.hfB;
    unsigned* cb_ = P.ctr + t * 32;

    if (bid < 16) {
      // ---- S1: x2 = relu(x1 @ in_w2^T + b2) ----
      const int mt = bid & 3, nt = bid >> 2;
      if (t > 0) waitctr(cb_ - 32 + 6 * 4 + mt, 4);      // x1done(t-1)
      gemmS<0>(P.x1f, nullptr, 0, P.w_in2, nullptr, mt * 64, nt * 256, P.b_in2, P.x2f);
      signalctr(cb_ + 0 * 4 + mt);

    } else if (bid < 48) {
      // ---- S2: gh (no wait on x2) ; wait x2 ; gi ; GRU gates -> hf ----
      const int idx = bid - 16, mt = idx & 3, ns = idx >> 2;   // ns 0..7
      const int mrow = mt * 64 + (wv & 3) * 16;
      const int cb = ns * 128 + (wv >> 2) * 64;
      f32x4 aR[4], aZ[4], aHN[4], aIN[4];
      #pragma unroll
      for (int nf = 0; nf < 4; ++nf) { aR[nf] = f32x4{0.f,0.f,0.f,0.f}; aZ[nf] = aR[nf]; aHN[nf] = aR[nf]; }
      if (t > 0) waitctr(cb_ - 32 + 1 * 4 + mt, 8);      // hdone(t-1)
      {
        const float* __restrict__ ap = hfPrev + (size_t)(mrow + l15) * 1024 + kq;
        const bf16* __restrict__ wb = P.w_whh + (size_t)(cb + l15) * 1024 + kq;
        #pragma unroll 2
        for (int k = 0; k < 1024; k += 32) {
          bf16x8 af = ld8bf(ap + k);
          #pragma unroll
          for (int nf = 0; nf < 4; ++nf) {
            aR[nf]  = MF(af, *(const bf16x8*)(wb + k + (size_t)nf * 16384),           aR[nf]);
            aZ[nf]  = MF(af, *(const bf16x8*)(wb + k + (size_t)nf * 16384 + 1048576), aZ[nf]);
            aHN[nf] = MF(af, *(const bf16x8*)(wb + k + (size_t)nf * 16384 + 2097152), aHN[nf]);
          }
        }
      }
      waitctr(cb_ + 0 * 4 + mt, 4);                      // x2done(t)
      #pragma unroll
      for (int nf = 0; nf < 4; ++nf) aIN[nf] = f32x4{0.f,0.f,0.f,0.f};
      {
        const float* __restrict__ ap = P.x2f + (size_t)(mrow + l15) * 1024 + kq;
        const bf16* __restrict__ wb = P.w_wih + (size_t)(cb + l15) * 1024 + kq;
        #pragma unroll 2
        for (int k = 0; k < 1024; k += 32) {
          bf16x8 af = ld8bf(ap + k);
          #pragma unroll
          for (int nf = 0; nf < 4; ++nf) {
            aR[nf]  = MF(af, *(const bf16x8*)(wb + k + (size_t)nf * 16384),           aR[nf]);
            aZ[nf]  = MF(af, *(const bf16x8*)(wb + k + (size_t)nf * 16384 + 1048576), aZ[nf]);
            aIN[nf] = MF(af, *(const bf16x8*)(wb + k + (size_t)nf * 16384 + 2097152), aIN[nf]);
          }
        }
      }
      #pragma unroll
      for (int nf = 0; nf < 4; ++nf) {
        const int col = cb + nf * 16 + l15;
        const float bir = P.b_ih[col], biz = P.b_ih[1024 + col], bin_ = P.b_ih[2048 + col];
        const float bhr = P.b_hh[col], bhz = P.b_hh[1024 + col], bhn = P.b_hh[2048 + col];
        #pragma unroll
        for (int r = 0; r < 4; ++r) {
          const int row = mrow + rq + r;
          float rr = aR[nf][r] + bir + bhr;
          float zz = aZ[nf][r] + biz + bhz;
          rr = 1.f / (1.f + __expf(-rr));
          zz = 1.f / (1.f + __expf(-zz));
          const float nn = tanhf(aIN[nf][r] + bin_ + rr * (aHN[nf][r] + bhn));
          const float h2 = (1.f - zz) * nn + zz * ldf(hfPrev + (size_t)row * 1024 + col);
          stf(hfCur + (size_t)row * 1024 + col, h2);
          P.feat[((size_t)row * T_ + t) * 1056 + col] = h2;
        }
      }
      signalctr(cb_ + 1 * 4 + mt);

    } else if (bid < 64) {
      // ---- S3q: q1 = relu(h @ w_po1h^T + obs_t @ w_po1o^T + b_po1) ----
      const int idx = bid - 48, mt = idx & 3, nt = idx >> 2;
      waitctr(cb_ + 1 * 4 + mt, 8);                      // hdone(t)
      gemmS<1>(hfCur, P.obsb + (size_t)t * 1024, (size_t)T_ * 1024,
               P.w_po1h, P.w_po1o, mt * 64, nt * 256, P.b_po1, P.q1f);
      signalctr(cb_ + 2 * 4 + mt);

    } else if (bid < 80) {
      // ---- S3p: pr1 ----
      const int idx = bid - 64, mt = idx & 3, nt = idx >> 2;
      waitctr(cb_ + 1 * 4 + mt, 8);
      gemmS<0>(hfCur, nullptr, 0, P.w_pr1, nullptr, mt * 64, nt * 256, P.b_pr1, P.p1f);
      signalctr(cb_ + 3 * 4 + mt);

    } else if (bid < 96) {
      // ---- S4q: q2 ----
      const int idx = bid - 80, mt = idx & 3, nt = idx >> 2;
      waitctr(cb_ + 2 * 4 + mt, 4);                      // q1done(t)
      gemmS<0>(P.q1f, nullptr, 0, P.w_po2, nullptr, mt * 64, nt * 256, P.b_po2, P.q2f);
      signalctr(cb_ + 4 * 4 + mt);

    } else if (bid < 112) {
      // ---- S4p: pr2 ----
      const int idx = bid - 96, mt = idx & 3, nt = idx >> 2;
      waitctr(cb_ + 3 * 4 + mt, 4);
      gemmS<0>(P.p1f, nullptr, 0, P.w_pr2, nullptr, mt * 64, nt * 256, P.b_pr2, P.p2f);
      signalctr(cb_ + 5 * 4 + mt);

    } else {
      // ---- S5: heads + stats + z + feat_z + next x1 (16 rows per block) ----
      const int g = bid - 112, m0 = g * 16, mt = g >> 2;
      waitctr(cb_ + 4 * 4 + mt, 4);                      // q2done(t)
      waitctr(cb_ + 5 * 4 + mt, 4);                      // p2done(t)
      float* zm = sh + 8448;                             // 16x32
      float* zs = zm + 512;
      float* zl = zs + 512;
      float* al = zl + 512;                              // 16x8
      {
        const int kw = wv & 3, half = wv >> 2;
        const float* __restrict__ A = half ? P.q2f : P.p2f;
        f32x4 c0{0.f,0.f,0.f,0.f}, c1 = c0, c2 = c0, c3 = c0;
        const float* __restrict__ ap = A + (size_t)(m0 + l15) * 1024 + kw * 256 + kq;
        const bf16* __restrict__ wp = P.w_head + (size_t)(half * 64 + l15) * 1024 + kw * 256 + kq;
        #pragma unroll
        for (int k = 0; k < 256; k += 32) {
          bf16x8 af = ld8bf(ap + k);
          c0 = MF(af, *(const bf16x8*)(wp + k            ), c0);
          c1 = MF(af, *(const bf16x8*)(wp + 16 * 1024 + k), c1);
          c2 = MF(af, *(const bf16x8*)(wp + 32 * 1024 + k), c2);
          c3 = MF(af, *(const bf16x8*)(wp + 48 * 1024 + k), c3);
        }
        f32x4 cc[4] = {c0, c1, c2, c3};
        float* s = sh + wv * 1056;
        #pragma unroll
        for (int t2 = 0; t2 < 4; ++t2)
          #pragma unroll
          for (int r = 0; r < 4; ++r)
            s[(rq + r) * 66 + t2 * 16 + l15] = cc[t2][r];
      }
      if (tid < 96) {
        const int r = tid / ACT_, k = tid - r * ACT_;
        al[r * 8 + k] = P.act[((size_t)(m0 + r) * T_ + t) * ACT_ + k];
      }
      __syncthreads();
      #pragma unroll
      for (int rep = 0; rep < 4; ++rep) {
        const int idx = rep * 512 + tid;                 // 16 rows x 128 cols
        const int r = idx >> 7, c = idx & 127;
        const int base = (c < 64) ? 0 : 4, cl = c & 63, j = c & 31;
        float v = sh[base * 1056 + r * 66 + cl] + sh[(base + 1) * 1056 + r * 66 + cl]
                + sh[(base + 2) * 1056 + r * 66 + cl] + sh[(base + 3) * 1056 + r * 66 + cl];
        const size_t ob = ((size_t)(m0 + r) * T_ + t) * STO_ + j;
        const int sel = c >> 5;
        if (sel == 0) {
          P.pm[ob] = v + P.pr_mb[j];
        } else if (sel == 1) {
          P.ps[ob] = __expf(fminf(fmaxf(v + P.pr_sb[j], -5.f), 2.f));
        } else if (sel == 2) {
          const float x = v + P.po_mb[j];
          P.qm[ob] = x; zm[r * 32 + j] = x;
        } else {
          const float x = __expf(fminf(fmaxf(v + P.po_sb[j], -5.f), 2.f));
          P.qs[ob] = x; zs[r * 32 + j] = x;
        }
      }
      __syncthreads();
      if (tid < 512) {
        const int r = tid >> 5, j = tid & 31;
        const float z = zm[r * 32 + j] + zs[r * 32 + j] * P.eps[((size_t)(m0 + r) * T_ + t) * STO_ + j];
        zl[r * 32 + j] = z;
        P.feat[((size_t)(m0 + r) * T_ + t) * 1056 + 1024 + j] = z;
      }
      __syncthreads();
      #pragma unroll
      for (int c2 = 0; c2 < 2; ++c2) {
        const int n = c2 * 512 + tid;
        const float* w = P.in_w1 + (size_t)n * 38;
        float wreg[38];
        #pragma unroll
        for (int j = 0; j < 38; ++j) wreg[j] = w[j];
        const float bn = P.in_b1[n];
        #pragma unroll 2
        for (int r = 0; r < 16; ++r) {
          float a = bn;
          #pragma unroll
          for (int k = 0; k < STO_; ++k) a = fmaf(zl[r * 32 + k], wreg[k], a);
          #pragma unroll
          for (int k = 0; k < ACT_; ++k) a = fmaf(al[r * 8 + k], wreg[32 + k], a);
          stf(P.x1f + (size_t)(m0 + r) * 1024 + n, fmaxf(a, 0.f));
        }
      }
      signalctr(cb_ + 6 * 4 + mt);
    }
  }
}

// ---------------- prologue ----------------
struct CvtArgs {
  const float *in_w2, *gru_wih, *gru_whh, *pr_w1, *pr_w2, *po_w1, *po_w2;
  const float *pr_mw, *pr_sw, *po_mw, *po_sw, *obs;
  bf16 *w_in2b, *w_wihb, *w_whhb, *w_pr1b, *w_pr2b, *w_po1hb, *w_po1ob, *w_po2b, *w_headb, *obsb;
};

__global__ void k_cvtall(CvtArgs a) {
  const int row = blockIdx.x;            // 28800 rows
  const float* src; bf16* dst;
  if      (row < 1024)  { src = a.in_w2   + (size_t)row * 1024;               dst = a.w_in2b  + (size_t)row * 1024; }
  else if (row < 4096)  { int r = row - 1024;  src = a.gru_wih + (size_t)r * 1024;        dst = a.w_wihb  + (size_t)r * 1024; }
  else if (row < 7168)  { int r = row - 4096;  src = a.gru_whh + (size_t)r * 1024;        dst = a.w_whhb  + (size_t)r * 1024; }
  else if (row < 8192)  { int r = row - 7168;  src = a.pr_w1   + (size_t)r * 1024;        dst = a.w_pr1b  + (size_t)r * 1024; }
  else if (row < 9216)  { int r = row - 8192;  src = a.pr_w2   + (size_t)r * 1024;        dst = a.w_pr2b  + (size_t)r * 1024; }
  else if (row < 10240) { int r = row - 9216;  src = a.po_w1   + (size_t)r * 2048;        dst = a.w_po1hb + (size_t)r * 1024; }
  else if (row < 11264) { int r = row - 10240; src = a.po_w1   + (size_t)r * 2048 + 1024; dst = a.w_po1ob + (size_t)r * 1024; }
  else if (row < 12288) { int r = row - 11264; src = a.po_w2   + (size_t)r * 1024;        dst = a.w_po2b  + (size_t)r * 1024; }
  else if (row < 12416) {
    int r = row - 12288;
    const float* hs[4] = { a.pr_mw, a.pr_sw, a.po_mw, a.po_sw };
    src = hs[r >> 5] + (size_t)(r & 31) * 1024;
    dst = a.w_headb + (size_t)r * 1024;
  }
  else { int r = row - 12416; src = a.obs + (size_t)r * 1024; dst = a.obsb + (size_t)r * 1024; }
  const int c = threadIdx.x * 4;
  float4 f = *(const float4*)(src + c);
  dst[c] = (bf16)f.x; dst[c + 1] = (bf16)f.y; dst[c + 2] = (bf16)f.z; dst[c + 3] = (bf16)f.w;
}

__global__ void k_init(const float* __restrict__ in_b1, float* __restrict__ x1f,
                       float* __restrict__ hfA, float* __restrict__ hfB) {
  const int i = blockIdx.x * 256 + threadIdx.x;      // < 262144
  x1f[i] = fmaxf(in_b1[i & 1023], 0.f);              // z0=0, a0=0
  hfA[i] = 0.f; hfB[i] = 0.f;
}

extern "C" void kernel_launch(void* const* d_in, const int* in_sizes, int n_in,
                              void* d_out, int out_size, void* d_ws, size_t ws_size,
                              hipStream_t stream) {
  (void)in_sizes; (void)n_in; (void)out_size; (void)ws_size;
  const float* obs      = (const float*)d_in[0];
  const float* actions  = (const float*)d_in[1];
  const float* eps_post = (const float*)d_in[3];   // eps_prior unused by the math
  const float* in_w1 = (const float*)d_in[4];
  const float* in_b1 = (const float*)d_in[5];
  const float* in_w2 = (const float*)d_in[6];
  const float* in_b2 = (const float*)d_in[7];
  const float* gru_wih = (const float*)d_in[8];
  const float* gru_whh = (const float*)d_in[9];
  const float* gru_bih = (const float*)d_in[10];
  const float* gru_bhh = (const float*)d_in[11];
  const float* pr_w1 = (const float*)d_in[12];
  const float* pr_b1 = (const float*)d_in[13];
  const float* pr_w2 = (const float*)d_in[14];
  const float* pr_b2 = (const float*)d_in[15];
  const float* pr_mw = (const float*)d_in[16];
  const float* pr_mb = (const float*)d_in[17];
  const float* pr_sw = (const float*)d_in[18];
  const float* pr_sb = (const float*)d_in[19];
  const float* po_w1 = (const float*)d_in[20];
  const float* po_b1 = (const float*)d_in[21];
  const float* po_w2 = (const float*)d_in[22];
  const float* po_b2 = (const float*)d_in[23];
  const float* po_mw = (const float*)d_in[24];
  const float* po_mb = (const float*)d_in[25];
  const float* po_sw = (const float*)d_in[26];
  const float* po_sb = (const float*)d_in[27];

  float* feat = (float*)d_out;
  float* pm = feat + (size_t)B_ * T_ * 1056;
  float* ps = pm + (size_t)B_ * T_ * STO_;
  float* qm = ps + (size_t)B_ * T_ * STO_;
  float* qs = qm + (size_t)B_ * T_ * STO_;

  char* wp_ = (char*)d_ws;
  auto carve = [&](size_t bytes) -> void* {
    void* r = (void*)wp_;
    wp_ += (bytes + 255) & ~(size_t)255;
    return r;
  };
  bf16* w_in2b  = (bf16*)carve((size_t)HID_ * HID_ * 2);
  bf16* w_wihb  = (bf16*)carve((size_t)3 * HID_ * HID_ * 2);
  bf16* w_whhb  = (bf16*)carve((size_t)3 * HID_ * HID_ * 2);
  bf16* w_pr1b  = (bf16*)carve((size_t)HID_ * HID_ * 2);
  bf16* w_pr2b  = (bf16*)carve((size_t)HID_ * HID_ * 2);
  bf16* w_po1hb = (bf16*)carve((size_t)HID_ * HID_ * 2);
  bf16* w_po1ob = (bf16*)carve((size_t)HID_ * OBS_ * 2);
  bf16* w_po2b  = (bf16*)carve((size_t)HID_ * HID_ * 2);
  bf16* w_headb = (bf16*)carve((size_t)128 * HID_ * 2);
  bf16* obsb    = (bf16*)carve((size_t)B_ * T_ * OBS_ * 2);
  float* x1f = (float*)carve((size_t)B_ * HID_ * 4);
  float* x2f = (float*)carve((size_t)B_ * HID_ * 4);
  float* q1f = (float*)carve((size_t)B_ * HID_ * 4);
  float* p1f = (float*)carve((size_t)B_ * HID_ * 4);
  float* q2f = (float*)carve((size_t)B_ * HID_ * 4);
  float* p2f = (float*)carve((size_t)B_ * HID_ * 4);
  float* hfA = (float*)carve((size_t)B_ * HID_ * 4);
  float* hfB = (float*)carve((size_t)B_ * HID_ * 4);
  unsigned* ctr = (unsigned*)carve((size_t)T_ * 32 * 4);

  (void)hipMemsetAsync(ctr, 0, (size_t)T_ * 32 * 4, stream);
  CvtArgs ca = { in_w2, gru_wih, gru_whh, pr_w1, pr_w2, po_w1, po_w2,
                 pr_mw, pr_sw, po_mw, po_sw, obs,
                 w_in2b, w_wihb, w_whhb, w_pr1b, w_pr2b, w_po1hb, w_po1ob, w_po2b, w_headb, obsb };
  k_cvtall<<<dim3(28800), dim3(256), 0, stream>>>(ca);
  k_init<<<dim3(1024), dim3(256), 0, stream>>>(in_b1, x1f, hfA, hfB);

  PP P;
  P.w_in2 = w_in2b; P.w_wih = w_wihb; P.w_whh = w_whhb; P.w_pr1 = w_pr1b; P.w_pr2 = w_pr2b;
  P.w_po1h = w_po1hb; P.w_po1o = w_po1ob; P.w_po2 = w_po2b; P.w_head = w_headb;
  P.obsb = obsb;
  P.b_in2 = in_b2; P.b_ih = gru_bih; P.b_hh = gru_bhh;
  P.b_pr1 = pr_b1; P.b_pr2 = pr_b2; P.b_po1 = po_b1; P.b_po2 = po_b2;
  P.pr_mb = pr_mb; P.pr_sb = pr_sb; P.po_mb = po_mb; P.po_sb = po_sb;
  P.eps = eps_post; P.act = actions; P.in_w1 = in_w1; P.in_b1 = in_b1;
  P.x1f = x1f; P.x2f = x2f; P.q1f = q1f; P.p1f = p1f; P.q2f = q2f; P.p2f = p2f;
  P.hfA = hfA; P.hfB = hfB;
  P.feat = feat; P.pm = pm; P.ps = ps; P.qm = qm; P.qs = qs;
  P.ctr = ctr;

  k_rssm<<<dim3(128), dim3(512), 0, stream>>>(P);
}

// Round 12
// 5791.183 us; speedup vs baseline: 6.8624x; 6.8624x over previous
//
#include <hip/hip_runtime.h>
#include <hip/hip_bf16.h>

#define B_   256
#define T_   64
#define OBS_ 1024
#define ACT_ 6
#define STO_ 32
#define HID_ 1024

using bf16 = __bf16;
typedef __attribute__((ext_vector_type(8))) __bf16 bf16x8;
typedef __attribute__((ext_vector_type(4))) float f32x4;

__device__ __forceinline__ f32x4 MF(bf16x8 a, bf16x8 b, f32x4 c) {
  return __builtin_amdgcn_mfma_f32_16x16x32_bf16(a, b, c, 0, 0, 0);
}

// ---------------- prologue: weights + obs -> bf16 ----------------
struct CvtArgs {
  const float *in_w2, *gru_wih, *gru_whh, *pr_w1, *pr_w2, *po_w1, *po_w2;
  const float *pr_mw, *pr_sw, *po_mw, *po_sw, *obs;
  bf16 *w_in2b, *w_wihb, *w_whhb, *w_pr1b, *w_pr2b, *w_po1hb, *w_po1ob, *w_po2b, *w_headb, *obsb;
};

__global__ void k_cvtall(CvtArgs a) {
  const int row = blockIdx.x;            // 28800 rows
  const float* src; bf16* dst;
  if      (row < 1024)  { src = a.in_w2   + (size_t)row * 1024;               dst = a.w_in2b  + (size_t)row * 1024; }
  else if (row < 4096)  { int r = row - 1024;  src = a.gru_wih + (size_t)r * 1024;        dst = a.w_wihb  + (size_t)r * 1024; }
  else if (row < 7168)  { int r = row - 4096;  src = a.gru_whh + (size_t)r * 1024;        dst = a.w_whhb  + (size_t)r * 1024; }
  else if (row < 8192)  { int r = row - 7168;  src = a.pr_w1   + (size_t)r * 1024;        dst = a.w_pr1b  + (size_t)r * 1024; }
  else if (row < 9216)  { int r = row - 8192;  src = a.pr_w2   + (size_t)r * 1024;        dst = a.w_pr2b  + (size_t)r * 1024; }
  else if (row < 10240) { int r = row - 9216;  src = a.po_w1   + (size_t)r * 2048;        dst = a.w_po1hb + (size_t)r * 1024; }
  else if (row < 11264) { int r = row - 10240; src = a.po_w1   + (size_t)r * 2048 + 1024; dst = a.w_po1ob + (size_t)r * 1024; }
  else if (row < 12288) { int r = row - 11264; src = a.po_w2   + (size_t)r * 1024;        dst = a.w_po2b  + (size_t)r * 1024; }
  else if (row < 12416) {
    int r = row - 12288;
    const float* hs[4] = { a.pr_mw, a.pr_sw, a.po_mw, a.po_sw };
    src = hs[r >> 5] + (size_t)(r & 31) * 1024;
    dst = a.w_headb + (size_t)r * 1024;
  }
  else { int r = row - 12416; src = a.obs + (size_t)r * 1024; dst = a.obsb + (size_t)r * 1024; }
  const int c = threadIdx.x * 4;
  float4 f = *(const float4*)(src + c);
  dst[c] = (bf16)f.x; dst[c + 1] = (bf16)f.y; dst[c + 2] = (bf16)f.z; dst[c + 3] = (bf16)f.w;
}

__global__ void k_init(const float* __restrict__ in_b1, bf16* __restrict__ x1b,
                       bf16* __restrict__ hbA, bf16* __restrict__ hbB,
                       float* __restrict__ hfA, float* __restrict__ hfB) {
  const int i = blockIdx.x * 256 + threadIdx.x;      // < 262144
  x1b[i] = (bf16)fmaxf(in_b1[i & 1023], 0.f);        // z0=0, a0=0
  hbA[i] = (bf16)0.f; hbB[i] = (bf16)0.f;
  hfA[i] = 0.f; hfB[i] = 0.f;
}

// ---------------- split-K dual-GEMM, two K-segments, bf16 out ----------------
// tile 16m x 64n; 4 waves K-split (kseg each); LDS reduce; relu; out bf16 ld 1024.
struct GB2 {
  const bf16 *A1, *A2, *W1, *W2;
  const float* bias;
  bf16* out;
  int lda1, lda2, K1, kseg;
};

__global__ __launch_bounds__(256, 4) void k_l1(GB2 g0, GB2 g1, int s1) {
  GB2 g; int tile;
  if ((int)blockIdx.x < s1) { g = g0; tile = blockIdx.x; }
  else                      { g = g1; tile = blockIdx.x - s1; }
  __shared__ float sh[3 * 1056];
  const int tid = threadIdx.x, lane = tid & 63, kw = tid >> 6;
  const int l15 = lane & 15, kg = lane >> 4, kq = kg * 8, rq = kg * 4;
  const int m0 = (tile & 15) * 16, n0 = (tile >> 4) * 64;
  const int kb = kw * g.kseg;

  const bf16* __restrict__ ap;
  const bf16* __restrict__ wp;
  if (kb < g.K1) {
    ap = g.A1 + (size_t)(m0 + l15) * g.lda1 + kb + kq;
    wp = g.W1 + (size_t)(n0 + l15) * 1024 + kb + kq;
  } else {
    ap = g.A2 + (size_t)(m0 + l15) * g.lda2 + (kb - g.K1) + kq;
    wp = g.W2 + (size_t)(n0 + l15) * 1024 + (kb - g.K1) + kq;
  }
  f32x4 c0{0.f,0.f,0.f,0.f}, c1 = c0, c2 = c0, c3 = c0;
  #pragma unroll 8
  for (int k = 0; k < g.kseg; k += 32) {
    bf16x8 af = *(const bf16x8*)(ap + k);
    c0 = MF(af, *(const bf16x8*)(wp + k            ), c0);
    c1 = MF(af, *(const bf16x8*)(wp + 16 * 1024 + k), c1);
    c2 = MF(af, *(const bf16x8*)(wp + 32 * 1024 + k), c2);
    c3 = MF(af, *(const bf16x8*)(wp + 48 * 1024 + k), c3);
  }
  f32x4 cc[4] = {c0, c1, c2, c3};
  if (kw) {
    float* s = sh + (kw - 1) * 1056;
    #pragma unroll
    for (int t2 = 0; t2 < 4; ++t2)
      #pragma unroll
      for (int r = 0; r < 4; ++r)
        s[(rq + r) * 66 + t2 * 16 + l15] = cc[t2][r];
  }
  __syncthreads();
  if (kw == 0) {
    #pragma unroll
    for (int t2 = 0; t2 < 4; ++t2) {
      const int n = n0 + t2 * 16 + l15;
      const float bv = g.bias[n];
      #pragma unroll
      for (int r = 0; r < 4; ++r) {
        float v = cc[t2][r] + bv;
        #pragma unroll
        for (int s = 0; s < 3; ++s)
          v += sh[s * 1056 + (rq + r) * 66 + t2 * 16 + l15];
        g.out[(size_t)(m0 + rq + r) * 1024 + n] = (bf16)fmaxf(v, 0.f);
      }
    }
  }
}

// ---------------- gh + gi + GRU gates fused (== R7 numerics) ----------------
// block (mt 0..3, cs 0..63): rows mt*64 (4 msub x 16), gate-cols cs*16..+16.
// 8 waves = 4 msub x 2 kw (K halves of 512).
__global__ __launch_bounds__(512, 2) void k_gru(
    const bf16* __restrict__ hbPrev, const float* __restrict__ hfPrev,
    bf16* __restrict__ hbCur, float* __restrict__ hfCur,
    const bf16* __restrict__ x2b, const bf16* __restrict__ wih,
    const bf16* __restrict__ whh, const float* __restrict__ bih,
    const float* __restrict__ bhh, float* __restrict__ feat, int t) {
  __shared__ float sh[4 * 1088];     // msub slots x 4 quantities x 16 x 17
  const int mt = blockIdx.x & 3, cs = blockIdx.x >> 2;
  const int tid = threadIdx.x, lane = tid & 63, wv = tid >> 6;
  const int msub = wv & 3, kw = wv >> 2;
  const int l15 = lane & 15, kg = lane >> 4, kq = kg * 8, rq = kg * 4;
  const int mrow = mt * 64 + msub * 16;
  const int c0 = cs * 16;
  const int kb = kw * 512;
  const size_t GOFF = (size_t)1024 * 1024;

  f32x4 ghR{0.f,0.f,0.f,0.f}, ghZ = ghR, ghN = ghR, giR = ghR, giZ = ghR, giN = ghR;
  {
    const bf16* __restrict__ ap = hbPrev + (size_t)(mrow + l15) * 1024 + kb + kq;
    const bf16* __restrict__ wr = whh + (size_t)(c0 + l15) * 1024 + kb + kq;
    #pragma unroll 4
    for (int k = 0; k < 512; k += 32) {
      bf16x8 af = *(const bf16x8*)(ap + k);
      ghR = MF(af, *(const bf16x8*)(wr + k           ), ghR);
      ghZ = MF(af, *(const bf16x8*)(wr + GOFF + k    ), ghZ);
      ghN = MF(af, *(const bf16x8*)(wr + 2 * GOFF + k), ghN);
    }
  }
  {
    const bf16* __restrict__ ap = x2b + (size_t)(mrow + l15) * 1024 + kb + kq;
    const bf16* __restrict__ wr = wih + (size_t)(c0 + l15) * 1024 + kb + kq;
    #pragma unroll 4
    for (int k = 0; k < 512; k += 32) {
      bf16x8 af = *(const bf16x8*)(ap + k);
      giR = MF(af, *(const bf16x8*)(wr + k           ), giR);
      giZ = MF(af, *(const bf16x8*)(wr + GOFF + k    ), giZ);
      giN = MF(af, *(const bf16x8*)(wr + 2 * GOFF + k), giN);
    }
  }
  f32x4 sR = ghR + giR, sZ = ghZ + giZ;
  if (kw) {
    float* s = sh + msub * 1088;
    #pragma unroll
    for (int r = 0; r < 4; ++r) {
      s[      (rq + r) * 17 + l15] = sR[r];
      s[272 + (rq + r) * 17 + l15] = sZ[r];
      s[544 + (rq + r) * 17 + l15] = giN[r];
      s[816 + (rq + r) * 17 + l15] = ghN[r];
    }
  }
  __syncthreads();
  if (kw == 0) {
    const int c = c0 + l15;
    const float bir = bih[c], biz = bih[1024 + c], bin_ = bih[2048 + c];
    const float bhr = bhh[c], bhz = bhh[1024 + c], bhn = bhh[2048 + c];
    const float* s = sh + msub * 1088;
    #pragma unroll
    for (int r = 0; r < 4; ++r) {
      const float vr  = sR[r]  + s[      (rq + r) * 17 + l15];
      const float vz  = sZ[r]  + s[272 + (rq + r) * 17 + l15];
      const float vin = giN[r] + s[544 + (rq + r) * 17 + l15];
      const float vhn = ghN[r] + s[816 + (rq + r) * 17 + l15];
      const int row = mrow + rq + r;
      float rr = vr + bir + bhr;
      float zz = vz + biz + bhz;
      rr = 1.f / (1.f + __expf(-rr));
      zz = 1.f / (1.f + __expf(-zz));
      const float nn = tanhf(vin + bin_ + rr * (vhn + bhn));
      const float h2 = (1.f - zz) * nn + zz * hfPrev[(size_t)row * 1024 + c];
      hbCur[(size_t)row * 1024 + c] = (bf16)h2;
      hfCur[(size_t)row * 1024 + c] = h2;
      feat[((size_t)row * T_ + t) * 1056 + c] = h2;
    }
  }
}

// ---------------- heads + stats + z + feat_z + next x1 (R6 verbatim) ----------------
__global__ __launch_bounds__(1024, 1) void k_headfin2(
    const bf16* __restrict__ p2b, const bf16* __restrict__ q2b,
    const bf16* __restrict__ whead,            // [128,1024]: pr_m, pr_s, po_m, po_s
    const float* __restrict__ pr_mb, const float* __restrict__ pr_sb,
    const float* __restrict__ po_mb, const float* __restrict__ po_sb,
    const float* __restrict__ eps, const float* __restrict__ act,
    const float* __restrict__ in_w1, const float* __restrict__ in_b1,
    float* __restrict__ pm, float* __restrict__ ps,
    float* __restrict__ qm, float* __restrict__ qs,
    float* __restrict__ feat, bf16* __restrict__ x1b, int t) {
  __shared__ float sh[8 * 1056];        // 8 waves x 16 x 66
  __shared__ float zm[16][32], zs[16][32], zl[16][32], al[16][8];
  const int g = blockIdx.x, m0 = g * 16;
  const int tid = threadIdx.x, lane = tid & 63, w = tid >> 6;
  const int l15 = lane & 15, kg = lane >> 4, kq = kg * 8, rq = kg * 4;

  if (w < 8) {
    const int kw = w & 3, half = w >> 2;
    const bf16* __restrict__ A = half ? q2b : p2b;
    f32x4 c0{0.f,0.f,0.f,0.f}, c1 = c0, c2 = c0, c3 = c0;
    const bf16* __restrict__ ap = A + (size_t)(m0 + l15) * 1024 + kw * 256 + kq;
    const bf16* __restrict__ wp = whead + (size_t)(half * 64 + l15) * 1024 + kw * 256 + kq;
    #pragma unroll
    for (int k = 0; k < 256; k += 32) {
      bf16x8 af = *(const bf16x8*)(ap + k);
      c0 = MF(af, *(const bf16x8*)(wp + k            ), c0);
      c1 = MF(af, *(const bf16x8*)(wp + 16 * 1024 + k), c1);
      c2 = MF(af, *(const bf16x8*)(wp + 32 * 1024 + k), c2);
      c3 = MF(af, *(const bf16x8*)(wp + 48 * 1024 + k), c3);
    }
    f32x4 cc[4] = {c0, c1, c2, c3};
    float* s = sh + w * 1056;
    #pragma unroll
    for (int t2 = 0; t2 < 4; ++t2)
      #pragma unroll
      for (int r = 0; r < 4; ++r)
        s[(rq + r) * 66 + t2 * 16 + l15] = cc[t2][r];
  }
  if (tid >= 928 && tid < 1024) {       // 96 threads: load actions
    const int idx = tid - 928, r = idx / ACT_, k = idx - r * ACT_;
    al[r][k] = act[((size_t)(m0 + r) * T_ + t) * ACT_ + k];
  }
  __syncthreads();

  #pragma unroll
  for (int rep = 0; rep < 2; ++rep) {
    const int idx = rep * 1024 + tid;   // 0..2047 = 16 rows x 128 cols
    const int r = idx >> 7, c = idx & 127;
    const int base = (c < 64) ? 0 : 4, cl = c & 63;
    float v = sh[base * 1056 + r * 66 + cl] + sh[(base + 1) * 1056 + r * 66 + cl]
            + sh[(base + 2) * 1056 + r * 66 + cl] + sh[(base + 3) * 1056 + r * 66 + cl];
    const size_t ob = ((size_t)(m0 + r) * T_ + t) * STO_ + (c & 31);
    const int sel = c >> 5;
    if (sel == 0) {
      pm[ob] = v + pr_mb[c];
    } else if (sel == 1) {
      ps[ob] = __expf(fminf(fmaxf(v + pr_sb[c - 32], -5.f), 2.f));
    } else if (sel == 2) {
      const float x = v + po_mb[c - 64];
      qm[ob] = x; zm[r][c - 64] = x;
    } else {
      const float x = __expf(fminf(fmaxf(v + po_sb[c - 96], -5.f), 2.f));
      qs[ob] = x; zs[r][c - 96] = x;
    }
  }
  __syncthreads();
  if (tid < 512) {
    const int r = tid >> 5, j = tid & 31;
    const float z = zm[r][j] + zs[r][j] * eps[((size_t)(m0 + r) * T_ + t) * STO_ + j];
    zl[r][j] = z;
    feat[((size_t)(m0 + r) * T_ + t) * 1056 + 1024 + j] = z;
  }
  __syncthreads();

  // x1_{t+1}: each thread owns output col n=tid for all 16 rows; w1 row in regs.
  const int n = tid;
  float wv_[38];
  #pragma unroll
  for (int j = 0; j < 38; ++j) wv_[j] = in_w1[(size_t)n * 38 + j];
  const float bn = in_b1[n];
  #pragma unroll 2
  for (int r = 0; r < 16; ++r) {
    float a = bn;
    #pragma unroll
    for (int k = 0; k < STO_; ++k) a = fmaf(zl[r][k], wv_[k], a);
    #pragma unroll
    for (int k = 0; k < ACT_; ++k) a = fmaf(al[r][k], wv_[32 + k], a);
    x1b[(size_t)(m0 + r) * 1024 + n] = (bf16)fmaxf(a, 0.f);
  }
}

extern "C" void kernel_launch(void* const* d_in, const int* in_sizes, int n_in,
                              void* d_out, int out_size, void* d_ws, size_t ws_size,
                              hipStream_t stream) {
  (void)in_sizes; (void)n_in; (void)out_size; (void)ws_size;
  const float* obs      = (const float*)d_in[0];
  const float* actions  = (const float*)d_in[1];
  const float* eps_post = (const float*)d_in[3];   // eps_prior unused by the math
  const float* in_w1 = (const float*)d_in[4];
  const float* in_b1 = (const float*)d_in[5];
  const float* in_w2 = (const float*)d_in[6];
  const float* in_b2 = (const float*)d_in[7];
  const float* gru_wih = (const float*)d_in[8];
  const float* gru_whh = (const float*)d_in[9];
  const float* gru_bih = (const float*)d_in[10];
  const float* gru_bhh = (const float*)d_in[11];
  const float* pr_w1 = (const float*)d_in[12];
  const float* pr_b1 = (const float*)d_in[13];
  const float* pr_w2 = (const float*)d_in[14];
  const float* pr_b2 = (const float*)d_in[15];
  const float* pr_mw = (const float*)d_in[16];
  const float* pr_mb = (const float*)d_in[17];
  const float* pr_sw = (const float*)d_in[18];
  const float* pr_sb = (const float*)d_in[19];
  const float* po_w1 = (const float*)d_in[20];
  const float* po_b1 = (const float*)d_in[21];
  const float* po_w2 = (const float*)d_in[22];
  const float* po_b2 = (const float*)d_in[23];
  const float* po_mw = (const float*)d_in[24];
  const float* po_mb = (const float*)d_in[25];
  const float* po_sw = (const float*)d_in[26];
  const float* po_sb = (const float*)d_in[27];

  float* feat = (float*)d_out;
  float* pm = feat + (size_t)B_ * T_ * 1056;
  float* ps = pm + (size_t)B_ * T_ * STO_;
  float* qm = ps + (size_t)B_ * T_ * STO_;
  float* qs = qm + (size_t)B_ * T_ * STO_;

  char* wp_ = (char*)d_ws;
  auto carve = [&](size_t bytes) -> void* {
    void* r = (void*)wp_;
    wp_ += (bytes + 255) & ~(size_t)255;
    return r;
  };
  bf16* w_in2b  = (bf16*)carve((size_t)HID_ * HID_ * 2);
  bf16* w_wihb  = (bf16*)carve((size_t)3 * HID_ * HID_ * 2);
  bf16* w_whhb  = (bf16*)carve((size_t)3 * HID_ * HID_ * 2);
  bf16* w_pr1b  = (bf16*)carve((size_t)HID_ * HID_ * 2);
  bf16* w_pr2b  = (bf16*)carve((size_t)HID_ * HID_ * 2);
  bf16* w_po1hb = (bf16*)carve((size_t)HID_ * HID_ * 2);
  bf16* w_po1ob = (bf16*)carve((size_t)HID_ * OBS_ * 2);
  bf16* w_po2b  = (bf16*)carve((size_t)HID_ * HID_ * 2);
  bf16* w_headb = (bf16*)carve((size_t)128 * HID_ * 2);
  bf16* obsb    = (bf16*)carve((size_t)B_ * T_ * OBS_ * 2);
  bf16* x1b = (bf16*)carve((size_t)B_ * HID_ * 2);
  bf16* x2b = (bf16*)carve((size_t)B_ * HID_ * 2);
  bf16* hbA = (bf16*)carve((size_t)B_ * HID_ * 2);
  bf16* hbB = (bf16*)carve((size_t)B_ * HID_ * 2);
  bf16* p1b = (bf16*)carve((size_t)B_ * HID_ * 2);
  bf16* q1b = (bf16*)carve((size_t)B_ * HID_ * 2);
  bf16* p2b = (bf16*)carve((size_t)B_ * HID_ * 2);
  bf16* q2b = (bf16*)carve((size_t)B_ * HID_ * 2);
  float* hfA = (float*)carve((size_t)B_ * HID_ * 4);
  float* hfB = (float*)carve((size_t)B_ * HID_ * 4);

  CvtArgs ca = { in_w2, gru_wih, gru_whh, pr_w1, pr_w2, po_w1, po_w2,
                 pr_mw, pr_sw, po_mw, po_sw, obs,
                 w_in2b, w_wihb, w_whhb, w_pr1b, w_pr2b, w_po1hb, w_po1ob, w_po2b, w_headb, obsb };
  k_cvtall<<<dim3(28800), dim3(256), 0, stream>>>(ca);
  k_init<<<dim3(1024), dim3(256), 0, stream>>>(in_b1, x1b, hbA, hbB, hfA, hfB);

  GB2 dummy = {};
  for (int t = 0; t < T_; ++t) {
    bf16* hbCur = (t & 1) ? hbB : hbA;
    bf16* hbPrev = (t & 1) ? hbA : hbB;
    float* hfCur = (t & 1) ? hfB : hfA;
    float* hfPrev = (t & 1) ? hfA : hfB;

    // K1: x2 = relu(x1 @ in_w2^T + b2)
    GB2 g_x2 = { x1b, nullptr, w_in2b, nullptr, in_b2, x2b, 1024, 0, 1024, 256 };
    k_l1<<<dim3(256), dim3(256), 0, stream>>>(g_x2, dummy, 256);

    // K2: gh + gi + gates -> h, feat_h
    k_gru<<<dim3(256), dim3(512), 0, stream>>>(
        hbPrev, hfPrev, hbCur, hfCur, x2b, w_wihb, w_whhb, gru_bih, gru_bhh, feat, t);

    // K3: pr1 (K=1024) || q1 (K=2048: h-part + obs-part)
    GB2 g_pr1 = { hbCur, nullptr, w_pr1b, nullptr, pr_b1, p1b, 1024, 0, 1024, 256 };
    GB2 g_q1  = { hbCur, obsb + (size_t)t * 1024, w_po1hb, w_po1ob, po_b1, q1b,
                  1024, T_ * 1024, 1024, 512 };
    k_l1<<<dim3(512), dim3(256), 0, stream>>>(g_pr1, g_q1, 256);

    // K4: pr2 || po2
    GB2 g_pr2 = { p1b, nullptr, w_pr2b, nullptr, pr_b2, p2b, 1024, 0, 1024, 256 };
    GB2 g_po2 = { q1b, nullptr, w_po2b, nullptr, po_b2, q2b, 1024, 0, 1024, 256 };
    k_l1<<<dim3(512), dim3(256), 0, stream>>>(g_pr2, g_po2, 256);

    // K5: heads + stats + z + feat_z + next x1 (R6 verbatim)
    k_headfin2<<<dim3(16), dim3(1024), 0, stream>>>(
        p2b, q2b, w_headb, pr_mb, pr_sb, po_mb, po_sb,
        eps_post, actions, in_w1, in_b1, pm, ps, qm, qs, feat, x1b, t);
  }
}